// Round 1
// 1649.259 us; speedup vs baseline: 1.2654x; 1.2654x over previous
//
#include <hip/hip_runtime.h>

#define B_ROWS 262144
#define ZDIM   128
#define ZHALF  64
#define HS     50
#define NFLOW  2
#define HSTRIDE 52   // padded h-row stride: 52*4 B = 208 B, 16B-aligned for ds_read_b128

__device__ __forceinline__ float frcp_(float x) { return __builtin_amdgcn_rcpf(x); }

__device__ __forceinline__ float tanh_fast(float x) {
    // tanh(x) = 1 - 2/(1+e^{2x}); exact at +-inf, ~1e-7 abs error
    float e = __expf(2.0f * x);
    return 1.0f - 2.0f * frcp_(e + 1.0f);
}

__device__ __forceinline__ float sigmoid_fast(float x) {
    return frcp_(1.0f + __expf(-x));
}

// ---------------------------------------------------------------------------
// Setup kernel: transpose W_mu / W_sig from [f][j(64)][k(50)] to
// [f][k(50)][j(64)] so phase-2 scalar (broadcast) loads are contiguous rows.
// ---------------------------------------------------------------------------
extern "C" __global__ void transpose_w(const float* __restrict__ Wmu,
                                       const float* __restrict__ Wsig,
                                       float* __restrict__ wt)
{
    int idx = blockIdx.x * 256 + threadIdx.x;
    const int TOT = NFLOW * 2 * ZHALF * HS;   // 12800
    if (idx >= TOT) return;
    int f   = idx / (ZHALF * HS);
    int rem = idx - f * (ZHALF * HS);
    int j   = rem / HS;
    int k   = rem - j * HS;
    int o   = f * (ZHALF * HS) + k * ZHALF + j;
    wt[o]        = Wmu[idx];
    wt[TOT + o]  = Wsig[idx];
}

// ---------------------------------------------------------------------------
// One coupling as a macro on NAMED register arrays (fully static indexing).
//   h = tanh(W0 @ ZIN + b0)           (h -> LDS row, j rolled, k unrolled)
//   sig = sigmoid(WTs^T h + bs); ZOUT *= sig; logdet += sum log sig
//   ZOUT += WTm^T h + bm
// Phase-2 runs in 32-wide chunks (acc[32]); h is read back as float4
// (ds_read_b128) so one LDS latency covers 128 FMAs, not 32.
// Weights are wave-uniform -> scalar (s_load) broadcast.
// ---------------------------------------------------------------------------
#define COUPLING(ZIN, ZOUT, I01)                                             \
{                                                                            \
    const float* W0c = W_in + (I01) * (HS * ZHALF);                          \
    const float* b0c = b_in + (I01) * HS;                                    \
    _Pragma("unroll 1")                                                      \
    for (int j = 0; j < HS; ++j) {                                           \
        const float* w = W0c + j * ZHALF;                                    \
        float a0 = 0.f, a1 = 0.f, a2 = 0.f, a3 = 0.f;                        \
        _Pragma("unroll")                                                    \
        for (int k = 0; k < ZHALF; k += 4) {                                 \
            a0 = __builtin_fmaf(ZIN[k + 0], w[k + 0], a0);                   \
            a1 = __builtin_fmaf(ZIN[k + 1], w[k + 1], a1);                   \
            a2 = __builtin_fmaf(ZIN[k + 2], w[k + 2], a2);                   \
            a3 = __builtin_fmaf(ZIN[k + 3], w[k + 3], a3);                   \
        }                                                                    \
        hrow[j] = tanh_fast(((a0 + a1) + (a2 + a3)) + b0c[j]);               \
    }                                                                        \
    const float* WTsc = WTsig + (I01) * (HS * ZHALF);                        \
    const float* WTmc = WTmu  + (I01) * (HS * ZHALF);                        \
    const float* bsc  = b_sig + (I01) * ZHALF;                               \
    const float* bmc  = b_mu  + (I01) * ZHALF;                               \
    _Pragma("unroll")                                                        \
    for (int c = 0; c < 2; ++c) {                                            \
        float acc[32];                                                       \
        _Pragma("unroll")                                                    \
        for (int j = 0; j < 32; ++j) acc[j] = 0.f;                           \
        _Pragma("unroll 1")                                                  \
        for (int k4 = 0; k4 < 48; k4 += 4) {                                 \
            float4 hq = *reinterpret_cast<const float4*>(hrow + k4);         \
            _Pragma("unroll")                                                \
            for (int kk = 0; kk < 4; ++kk) {                                 \
                float hv = (kk == 0) ? hq.x : (kk == 1) ? hq.y               \
                         : (kk == 2) ? hq.z : hq.w;                          \
                const float* w = WTsc + (k4 + kk) * ZHALF + c * 32;          \
                _Pragma("unroll")                                            \
                for (int j = 0; j < 32; ++j)                                 \
                    acc[j] = __builtin_fmaf(hv, w[j], acc[j]);               \
            }                                                                \
        }                                                                    \
        {                                                                    \
            float2 ht = *reinterpret_cast<const float2*>(hrow + 48);         \
            const float* w0 = WTsc + 48 * ZHALF + c * 32;                    \
            const float* w1 = WTsc + 49 * ZHALF + c * 32;                    \
            _Pragma("unroll")                                                \
            for (int j = 0; j < 32; ++j)                                     \
                acc[j] = __builtin_fmaf(ht.x, w0[j], acc[j]);                \
            _Pragma("unroll")                                                \
            for (int j = 0; j < 32; ++j)                                     \
                acc[j] = __builtin_fmaf(ht.y, w1[j], acc[j]);                \
        }                                                                    \
        _Pragma("unroll")                                                    \
        for (int j = 0; j < 32; ++j) {                                       \
            float sg = sigmoid_fast(acc[j] + bsc[c * 32 + j]);               \
            ZOUT[c * 32 + j] *= sg;                                          \
            float lg = __logf(sg);                                           \
            if ((j & 3) == 0)      ld0 += lg;                                \
            else if ((j & 3) == 1) ld1 += lg;                                \
            else if ((j & 3) == 2) ld2 += lg;                                \
            else                   ld3 += lg;                                \
        }                                                                    \
    }                                                                        \
    _Pragma("unroll")                                                        \
    for (int c = 0; c < 2; ++c) {                                            \
        float acc[32];                                                       \
        _Pragma("unroll")                                                    \
        for (int j = 0; j < 32; ++j) acc[j] = 0.f;                           \
        _Pragma("unroll 1")                                                  \
        for (int k4 = 0; k4 < 48; k4 += 4) {                                 \
            float4 hq = *reinterpret_cast<const float4*>(hrow + k4);         \
            _Pragma("unroll")                                                \
            for (int kk = 0; kk < 4; ++kk) {                                 \
                float hv = (kk == 0) ? hq.x : (kk == 1) ? hq.y               \
                         : (kk == 2) ? hq.z : hq.w;                          \
                const float* w = WTmc + (k4 + kk) * ZHALF + c * 32;          \
                _Pragma("unroll")                                            \
                for (int j = 0; j < 32; ++j)                                 \
                    acc[j] = __builtin_fmaf(hv, w[j], acc[j]);               \
            }                                                                \
        }                                                                    \
        {                                                                    \
            float2 ht = *reinterpret_cast<const float2*>(hrow + 48);         \
            const float* w0 = WTmc + 48 * ZHALF + c * 32;                    \
            const float* w1 = WTmc + 49 * ZHALF + c * 32;                    \
            _Pragma("unroll")                                                \
            for (int j = 0; j < 32; ++j)                                     \
                acc[j] = __builtin_fmaf(ht.x, w0[j], acc[j]);                \
            _Pragma("unroll")                                                \
            for (int j = 0; j < 32; ++j)                                     \
                acc[j] = __builtin_fmaf(ht.y, w1[j], acc[j]);                \
        }                                                                    \
        _Pragma("unroll")                                                    \
        for (int j = 0; j < 32; ++j)                                         \
            ZOUT[c * 32 + j] += acc[j] + bmc[c * 32 + j];                    \
    }                                                                        \
}

// ---------------------------------------------------------------------------
// Main kernel: 256 rows/block, one row per thread. z1/z2 register-resident
// (static indices only); h in LDS (stride 52 -> 16B-aligned b128 readback).
// amdgpu_waves_per_eu(2,2) PINS the allocator to the 2-wave/EU tier
// (256-VGPR budget): previous build allocated 128 VGPRs and spilled z1/z2
// to scratch (457 MB excess WRITE_SIZE, VALUBusy 11%).
// LDS 53.2 KB union: {zbuf,qbuf} staging (phase A/C) and h rows (phase B).
// ---------------------------------------------------------------------------
extern "C" __global__ __launch_bounds__(256)
__attribute__((amdgpu_waves_per_eu(2, 2))) void flow_main(
    const float* __restrict__ mean, const float* __restrict__ logvar,
    const float* __restrict__ eps,  const float* __restrict__ W_in,
    const float* __restrict__ b_in, const float* __restrict__ b_mu,
    const float* __restrict__ b_sig,const float* __restrict__ WTmu,
    const float* __restrict__ WTsig, float* __restrict__ out)
{
    __shared__ float smem[256 * HSTRIDE];      // 53248 B
    float* zbuf = smem;                        // [256][17]
    float* qbuf = smem + 256 * 17;             // [256][17]

    const int tid  = threadIdx.x;
    const int row0 = blockIdx.x * 256;
    const int colA = tid & 15;
    const int rsegA = tid >> 4;                // 0..15

    float z1[ZHALF];
    float z2[ZHALF];
    float qsum = 0.0f;

    // ---- Phase A: coalesced load, z = eps*exp(0.5 lv)+mean, LDS transpose ----
    #pragma unroll
    for (int c = 0; c < 8; ++c) {
        #pragma unroll
        for (int s = 0; s < 16; ++s) {
            int row = rsegA + (s << 4);
            int g = (row0 + row) * ZDIM + c * 16 + colA;
            float m  = mean[g];
            float lv = logvar[g];
            float e  = eps[g];
            zbuf[row * 17 + colA] = __builtin_fmaf(e, __expf(0.5f * lv), m);
            qbuf[row * 17 + colA] = __builtin_fmaf(e, e, lv);   // eps^2 + logvar
        }
        __syncthreads();
        #pragma unroll
        for (int k = 0; k < 16; ++k) {
            float zv = zbuf[tid * 17 + k];
            if (c < 4) z1[c * 16 + k] = zv;
            else       z2[(c - 4) * 16 + k] = zv;
            qsum += qbuf[tid * 17 + k];
        }
        __syncthreads();
    }
    // logqz0 = -0.5*(sum logvar + sum eps^2)  [exact: (z-mean)^2/exp(lv)=eps^2]
    const float logqz0 = -0.5f * qsum;

    // ---- Phase B: 4 couplings ----
    float* hrow = smem + tid * HSTRIDE;
    float ld0 = 0.f, ld1 = 0.f, ld2 = 0.f, ld3 = 0.f;

    COUPLING(z1, z2, 0)   // flow 0, half 0: z1 conditions z2
    COUPLING(z2, z1, 1)   // flow 0, half 1: z2 conditions z1
    COUPLING(z1, z2, 2)   // flow 1, half 0
    COUPLING(z2, z1, 3)   // flow 1, half 1

    const float logdet = (ld0 + ld1) + (ld2 + ld3);
    const float logqz  = logqz0 - logdet;

    float p0 = 0.f, p1 = 0.f, p2 = 0.f, p3 = 0.f;
    #pragma unroll
    for (int j = 0; j < ZHALF; j += 4) {
        p0 = __builtin_fmaf(z1[j + 0], z1[j + 0], p0);
        p1 = __builtin_fmaf(z1[j + 1], z1[j + 1], p1);
        p2 = __builtin_fmaf(z1[j + 2], z1[j + 2], p2);
        p3 = __builtin_fmaf(z1[j + 3], z1[j + 3], p3);
    }
    #pragma unroll
    for (int j = 0; j < ZHALF; j += 4) {
        p0 = __builtin_fmaf(z2[j + 0], z2[j + 0], p0);
        p1 = __builtin_fmaf(z2[j + 1], z2[j + 1], p1);
        p2 = __builtin_fmaf(z2[j + 2], z2[j + 2], p2);
        p3 = __builtin_fmaf(z2[j + 3], z2[j + 3], p3);
    }
    const float logpz = -0.5f * ((p0 + p1) + (p2 + p3));

    // ---- Phase C: LDS transpose back, coalesced store of z ----
    #pragma unroll
    for (int c = 0; c < 8; ++c) {
        __syncthreads();   // first iteration also guards h-region reuse
        #pragma unroll
        for (int k = 0; k < 16; ++k) {
            float zv = (c < 4) ? z1[c * 16 + k] : z2[(c - 4) * 16 + k];
            zbuf[tid * 17 + k] = zv;
        }
        __syncthreads();
        #pragma unroll
        for (int s = 0; s < 16; ++s) {
            int row = rsegA + (s << 4);
            out[(size_t)(row0 + row) * ZDIM + c * 16 + colA] = zbuf[row * 17 + colA];
        }
    }
    const size_t zEnd = (size_t)B_ROWS * ZDIM;
    out[zEnd + row0 + tid]          = logpz;
    out[zEnd + B_ROWS + row0 + tid] = logqz;
}

extern "C" void kernel_launch(void* const* d_in, const int* in_sizes, int n_in,
                              void* d_out, int out_size, void* d_ws, size_t ws_size,
                              hipStream_t stream)
{
    const float* mean   = (const float*)d_in[0];
    const float* logvar = (const float*)d_in[1];
    const float* eps    = (const float*)d_in[2];
    const float* W_in   = (const float*)d_in[3];
    const float* b_in   = (const float*)d_in[4];
    const float* W_mu   = (const float*)d_in[5];
    const float* b_mu   = (const float*)d_in[6];
    const float* W_sig  = (const float*)d_in[7];
    const float* b_sig  = (const float*)d_in[8];
    float* out = (float*)d_out;
    float* wt  = (float*)d_ws;      // needs 2*12800*4 = 102400 B of scratch

    transpose_w<<<50, 256, 0, stream>>>(W_mu, W_sig, wt);
    flow_main<<<B_ROWS / 256, 256, 0, stream>>>(mean, logvar, eps, W_in, b_in,
                                                b_mu, b_sig, wt, wt + 12800, out);
}

// Round 2
// 1440.892 us; speedup vs baseline: 1.4484x; 1.1446x over previous
//
#include <hip/hip_runtime.h>

#define B_ROWS 262144
#define ZDIM   128
#define ZHALF  64
#define HS     50
#define NFLOW  2
#define HSTRIDE 52   // padded h-row stride: 52*4 B = 208 B, 16B-aligned; lanes 0-7
                     // cover all 32 banks for b128 ops -> conflict-free r/w

__device__ __forceinline__ float frcp_(float x) { return __builtin_amdgcn_rcpf(x); }

__device__ __forceinline__ float tanh_fast(float x) {
    // tanh(x) = 1 - 2/(1+e^{2x}); exact at +-inf, ~1e-7 abs error
    float e = __expf(2.0f * x);
    return 1.0f - 2.0f * frcp_(e + 1.0f);
}

__device__ __forceinline__ float sigmoid_fast(float x) {
    return frcp_(1.0f + __expf(-x));
}

// ---------------------------------------------------------------------------
// Setup kernel: transpose W_mu / W_sig from [f][j(64)][k(50)] to
// [f][k(50)][j(64)] so phase-2 scalar (broadcast) loads are contiguous rows.
// ---------------------------------------------------------------------------
extern "C" __global__ void transpose_w(const float* __restrict__ Wmu,
                                       const float* __restrict__ Wsig,
                                       float* __restrict__ wt)
{
    int idx = blockIdx.x * 256 + threadIdx.x;
    const int TOT = NFLOW * 2 * ZHALF * HS;   // 12800
    if (idx >= TOT) return;
    int f   = idx / (ZHALF * HS);
    int rem = idx - f * (ZHALF * HS);
    int j   = rem / HS;
    int k   = rem - j * HS;
    int o   = f * (ZHALF * HS) + k * ZHALF + j;
    wt[o]        = Wmu[idx];
    wt[TOT + o]  = Wsig[idx];
}

// ---------------------------------------------------------------------------
// One coupling as a macro on NAMED register arrays (fully static indexing).
// Phase 1: h = tanh(W0 @ ZIN + b0), produced 4 rows at a time (4 independent
//          64-FMA chains) and written to LDS via ds_write_b128 (conflict-free
//          at stride 52).
// Phase 2: sig pass then mu pass, 32-wide acc chunks; h read back as float4.
// Weights are wave-uniform -> scalar (s_load) broadcast.
// ---------------------------------------------------------------------------
#define COUPLING(ZIN, ZOUT, I01)                                             \
{                                                                            \
    const float* W0c = W_in + (I01) * (HS * ZHALF);                          \
    const float* b0c = b_in + (I01) * HS;                                    \
    _Pragma("unroll 1")                                                      \
    for (int j0 = 0; j0 < 48; j0 += 4) {                                     \
        const float* w0 = W0c + (j0 + 0) * ZHALF;                            \
        const float* w1 = W0c + (j0 + 1) * ZHALF;                            \
        const float* w2 = W0c + (j0 + 2) * ZHALF;                            \
        const float* w3 = W0c + (j0 + 3) * ZHALF;                            \
        float s0 = 0.f, s1 = 0.f, s2 = 0.f, s3 = 0.f;                        \
        _Pragma("unroll")                                                    \
        for (int k = 0; k < ZHALF; ++k) {                                    \
            float zv = ZIN[k];                                               \
            s0 = __builtin_fmaf(zv, w0[k], s0);                              \
            s1 = __builtin_fmaf(zv, w1[k], s1);                              \
            s2 = __builtin_fmaf(zv, w2[k], s2);                              \
            s3 = __builtin_fmaf(zv, w3[k], s3);                              \
        }                                                                    \
        float4 hv;                                                           \
        hv.x = tanh_fast(s0 + b0c[j0 + 0]);                                  \
        hv.y = tanh_fast(s1 + b0c[j0 + 1]);                                  \
        hv.z = tanh_fast(s2 + b0c[j0 + 2]);                                  \
        hv.w = tanh_fast(s3 + b0c[j0 + 3]);                                  \
        *reinterpret_cast<float4*>(hrow + j0) = hv;                          \
    }                                                                        \
    {                                                                        \
        const float* w0 = W0c + 48 * ZHALF;                                  \
        const float* w1 = W0c + 49 * ZHALF;                                  \
        float s0 = 0.f, s1 = 0.f;                                            \
        _Pragma("unroll")                                                    \
        for (int k = 0; k < ZHALF; ++k) {                                    \
            float zv = ZIN[k];                                               \
            s0 = __builtin_fmaf(zv, w0[k], s0);                              \
            s1 = __builtin_fmaf(zv, w1[k], s1);                              \
        }                                                                    \
        float2 ht;                                                           \
        ht.x = tanh_fast(s0 + b0c[48]);                                      \
        ht.y = tanh_fast(s1 + b0c[49]);                                      \
        *reinterpret_cast<float2*>(hrow + 48) = ht;                          \
    }                                                                        \
    const float* WTsc = WTsig + (I01) * (HS * ZHALF);                        \
    const float* WTmc = WTmu  + (I01) * (HS * ZHALF);                        \
    const float* bsc  = b_sig + (I01) * ZHALF;                               \
    const float* bmc  = b_mu  + (I01) * ZHALF;                               \
    _Pragma("unroll")                                                        \
    for (int c = 0; c < 2; ++c) {                                            \
        float acc[32];                                                       \
        _Pragma("unroll")                                                    \
        for (int j = 0; j < 32; ++j) acc[j] = 0.f;                           \
        _Pragma("unroll 1")                                                  \
        for (int k4 = 0; k4 < 48; k4 += 4) {                                 \
            float4 hq = *reinterpret_cast<const float4*>(hrow + k4);         \
            _Pragma("unroll")                                                \
            for (int kk = 0; kk < 4; ++kk) {                                 \
                float hv = (kk == 0) ? hq.x : (kk == 1) ? hq.y               \
                         : (kk == 2) ? hq.z : hq.w;                          \
                const float* w = WTsc + (k4 + kk) * ZHALF + c * 32;          \
                _Pragma("unroll")                                            \
                for (int j = 0; j < 32; ++j)                                 \
                    acc[j] = __builtin_fmaf(hv, w[j], acc[j]);               \
            }                                                                \
        }                                                                    \
        {                                                                    \
            float2 ht = *reinterpret_cast<const float2*>(hrow + 48);         \
            const float* w0 = WTsc + 48 * ZHALF + c * 32;                    \
            const float* w1 = WTsc + 49 * ZHALF + c * 32;                    \
            _Pragma("unroll")                                                \
            for (int j = 0; j < 32; ++j)                                     \
                acc[j] = __builtin_fmaf(ht.x, w0[j], acc[j]);                \
            _Pragma("unroll")                                                \
            for (int j = 0; j < 32; ++j)                                     \
                acc[j] = __builtin_fmaf(ht.y, w1[j], acc[j]);                \
        }                                                                    \
        _Pragma("unroll")                                                    \
        for (int j = 0; j < 32; ++j) {                                       \
            float sg = sigmoid_fast(acc[j] + bsc[c * 32 + j]);               \
            ZOUT[c * 32 + j] *= sg;                                          \
            float lg = __logf(sg);                                           \
            if ((j & 3) == 0)      ld0 += lg;                                \
            else if ((j & 3) == 1) ld1 += lg;                                \
            else if ((j & 3) == 2) ld2 += lg;                                \
            else                   ld3 += lg;                                \
        }                                                                    \
    }                                                                        \
    _Pragma("unroll")                                                        \
    for (int c = 0; c < 2; ++c) {                                            \
        float acc[32];                                                       \
        _Pragma("unroll")                                                    \
        for (int j = 0; j < 32; ++j) acc[j] = 0.f;                           \
        _Pragma("unroll 1")                                                  \
        for (int k4 = 0; k4 < 48; k4 += 4) {                                 \
            float4 hq = *reinterpret_cast<const float4*>(hrow + k4);         \
            _Pragma("unroll")                                                \
            for (int kk = 0; kk < 4; ++kk) {                                 \
                float hv = (kk == 0) ? hq.x : (kk == 1) ? hq.y               \
                         : (kk == 2) ? hq.z : hq.w;                          \
                const float* w = WTmc + (k4 + kk) * ZHALF + c * 32;          \
                _Pragma("unroll")                                            \
                for (int j = 0; j < 32; ++j)                                 \
                    acc[j] = __builtin_fmaf(hv, w[j], acc[j]);               \
            }                                                                \
        }                                                                    \
        {                                                                    \
            float2 ht = *reinterpret_cast<const float2*>(hrow + 48);         \
            const float* w0 = WTmc + 48 * ZHALF + c * 32;                    \
            const float* w1 = WTmc + 49 * ZHALF + c * 32;                    \
            _Pragma("unroll")                                                \
            for (int j = 0; j < 32; ++j)                                     \
                acc[j] = __builtin_fmaf(ht.x, w0[j], acc[j]);                \
            _Pragma("unroll")                                                \
            for (int j = 0; j < 32; ++j)                                     \
                acc[j] = __builtin_fmaf(ht.y, w1[j], acc[j]);                \
        }                                                                    \
        _Pragma("unroll")                                                    \
        for (int j = 0; j < 32; ++j)                                         \
            ZOUT[c * 32 + j] += acc[j] + bmc[c * 32 + j];                    \
    }                                                                        \
}

// ---------------------------------------------------------------------------
// Main kernel: 256 rows/block, one row per thread. z1/z2 register-resident
// (static indices only); h in LDS (stride 52, b128 r/w conflict-free).
// Register budget: demand ~180 VGPRs.  Round-1's amdgpu_waves_per_eu(2,2)
// was ignored (VGPR_Count stayed 128 -> ~500 MB scratch spill traffic), so
// force the 256-reg tier two ways: __launch_bounds__(256, 2) (min 2
// waves/EU) AND amdgpu_num_vgpr(256) (direct allocator budget).
// Occupancy is LDS-capped at 2 blocks/CU anyway, so no occupancy loss.
// ---------------------------------------------------------------------------
extern "C" __global__ __launch_bounds__(256, 2)
__attribute__((amdgpu_num_vgpr(256))) void flow_main(
    const float* __restrict__ mean, const float* __restrict__ logvar,
    const float* __restrict__ eps,  const float* __restrict__ W_in,
    const float* __restrict__ b_in, const float* __restrict__ b_mu,
    const float* __restrict__ b_sig,const float* __restrict__ WTmu,
    const float* __restrict__ WTsig, float* __restrict__ out)
{
    __shared__ float smem[256 * HSTRIDE];      // 53248 B
    float* zbuf = smem;                        // [256][17]
    float* qbuf = smem + 256 * 17;             // [256][17]

    const int tid  = threadIdx.x;
    const int row0 = blockIdx.x * 256;
    const int colA = tid & 15;
    const int rsegA = tid >> 4;                // 0..15

    float z1[ZHALF];
    float z2[ZHALF];
    float qsum = 0.0f;

    // ---- Phase A: coalesced load, z = eps*exp(0.5 lv)+mean, LDS transpose ----
    #pragma unroll
    for (int c = 0; c < 8; ++c) {
        #pragma unroll
        for (int s = 0; s < 16; ++s) {
            int row = rsegA + (s << 4);
            int g = (row0 + row) * ZDIM + c * 16 + colA;
            float m  = mean[g];
            float lv = logvar[g];
            float e  = eps[g];
            zbuf[row * 17 + colA] = __builtin_fmaf(e, __expf(0.5f * lv), m);
            qbuf[row * 17 + colA] = __builtin_fmaf(e, e, lv);   // eps^2 + logvar
        }
        __syncthreads();
        #pragma unroll
        for (int k = 0; k < 16; ++k) {
            float zv = zbuf[tid * 17 + k];
            if (c < 4) z1[c * 16 + k] = zv;
            else       z2[(c - 4) * 16 + k] = zv;
            qsum += qbuf[tid * 17 + k];
        }
        __syncthreads();
    }
    // logqz0 = -0.5*(sum logvar + sum eps^2)  [exact: (z-mean)^2/exp(lv)=eps^2]
    const float logqz0 = -0.5f * qsum;

    // ---- Phase B: 4 couplings ----
    float* hrow = smem + tid * HSTRIDE;
    float ld0 = 0.f, ld1 = 0.f, ld2 = 0.f, ld3 = 0.f;

    COUPLING(z1, z2, 0)   // flow 0, half 0: z1 conditions z2
    COUPLING(z2, z1, 1)   // flow 0, half 1: z2 conditions z1
    COUPLING(z1, z2, 2)   // flow 1, half 0
    COUPLING(z2, z1, 3)   // flow 1, half 1

    const float logdet = (ld0 + ld1) + (ld2 + ld3);
    const float logqz  = logqz0 - logdet;

    float p0 = 0.f, p1 = 0.f, p2 = 0.f, p3 = 0.f;
    #pragma unroll
    for (int j = 0; j < ZHALF; j += 4) {
        p0 = __builtin_fmaf(z1[j + 0], z1[j + 0], p0);
        p1 = __builtin_fmaf(z1[j + 1], z1[j + 1], p1);
        p2 = __builtin_fmaf(z1[j + 2], z1[j + 2], p2);
        p3 = __builtin_fmaf(z1[j + 3], z1[j + 3], p3);
    }
    #pragma unroll
    for (int j = 0; j < ZHALF; j += 4) {
        p0 = __builtin_fmaf(z2[j + 0], z2[j + 0], p0);
        p1 = __builtin_fmaf(z2[j + 1], z2[j + 1], p1);
        p2 = __builtin_fmaf(z2[j + 2], z2[j + 2], p2);
        p3 = __builtin_fmaf(z2[j + 3], z2[j + 3], p3);
    }
    const float logpz = -0.5f * ((p0 + p1) + (p2 + p3));

    // ---- Phase C: LDS transpose back, coalesced store of z ----
    #pragma unroll
    for (int c = 0; c < 8; ++c) {
        __syncthreads();   // first iteration also guards h-region reuse
        #pragma unroll
        for (int k = 0; k < 16; ++k) {
            float zv = (c < 4) ? z1[c * 16 + k] : z2[(c - 4) * 16 + k];
            zbuf[tid * 17 + k] = zv;
        }
        __syncthreads();
        #pragma unroll
        for (int s = 0; s < 16; ++s) {
            int row = rsegA + (s << 4);
            out[(size_t)(row0 + row) * ZDIM + c * 16 + colA] = zbuf[row * 17 + colA];
        }
    }
    const size_t zEnd = (size_t)B_ROWS * ZDIM;
    out[zEnd + row0 + tid]          = logpz;
    out[zEnd + B_ROWS + row0 + tid] = logqz;
}

extern "C" void kernel_launch(void* const* d_in, const int* in_sizes, int n_in,
                              void* d_out, int out_size, void* d_ws, size_t ws_size,
                              hipStream_t stream)
{
    const float* mean   = (const float*)d_in[0];
    const float* logvar = (const float*)d_in[1];
    const float* eps    = (const float*)d_in[2];
    const float* W_in   = (const float*)d_in[3];
    const float* b_in   = (const float*)d_in[4];
    const float* W_mu   = (const float*)d_in[5];
    const float* b_mu   = (const float*)d_in[6];
    const float* W_sig  = (const float*)d_in[7];
    const float* b_sig  = (const float*)d_in[8];
    float* out = (float*)d_out;
    float* wt  = (float*)d_ws;      // needs 2*12800*4 = 102400 B of scratch

    transpose_w<<<50, 256, 0, stream>>>(W_mu, W_sig, wt);
    flow_main<<<B_ROWS / 256, 256, 0, stream>>>(mean, logvar, eps, W_in, b_in,
                                                b_mu, b_sig, wt, wt + 12800, out);
}